// Round 5
// baseline (540.429 us; speedup 1.0000x reference)
//
#include <hip/hip_runtime.h>
#include <hip/hip_fp16.h>

// Fused int4-dequant GEMM (Marlin forward): C = A @ (unpack(B)-8)*s
// A: (8192, 4096) fp32   B: (512, 4096) int32 (8 nibbles along k)   s: (32, 4096) fp32
// C: (8192, 4096) fp32
//
// 128x128x64 tile, 256 threads (4 waves, 64x64/wave), mfma_f32_16x16x32_f16.
// A cvt fp32->fp16 during staging (cvt_pkrtz, k-permuted pairs); B unpacked
// with the 0x6400 fp16 bit-trick (exact ints) then scaled once in fp16.
// LDS swizzles: A tile byte ^= (row&7)<<4; B tile byte ^= ((row&7)^((row>>3)&3))<<4
// (extra row bits needed because B-staging writes 4 consecutive rows/thread).
// Pipelined: issue global loads for tile kt+1 BEFORE compute of kt (T14).

constexpr int MDIM = 8192;
constexpr int NDIM = 4096;
constexpr int KDIM = 4096;
constexpr int BM = 128;
constexpr int BN = 128;
constexpr int BK = 64;
constexpr int THREADS = 256;
constexpr int KSTEPS = KDIM / BK;   // 64

typedef _Float16 f16x8 __attribute__((ext_vector_type(8)));
typedef float f32x4 __attribute__((ext_vector_type(4)));

__device__ __forceinline__ unsigned int pack_dq(unsigned int q, __half2 k1032,
                                                __half2 sh) {
  __half2 h = __builtin_bit_cast(__half2, q);   // (1024+nib_lo, 1024+nib_hi)
  h = __hmul2(__hsub2(h, k1032), sh);           // (nib-8)*s, sub exact
  return __builtin_bit_cast(unsigned int, h);
}

__device__ __forceinline__ unsigned int cvt2(float lo, float hi) {
  auto p = __builtin_amdgcn_cvt_pkrtz(lo, hi);  // __fp16 ext_vector(2)
  return __builtin_bit_cast(unsigned int, p);
}

__global__ __launch_bounds__(THREADS, 2)
void marlin_fused(const float* __restrict__ A, const int* __restrict__ Bq,
                  const float* __restrict__ S, float* __restrict__ C) {
  __shared__ char lds[(BM * BK + BN * BK) * 2];   // 16 KiB A + 16 KiB B (fp16)
  char* As = lds;
  char* Bs = lds + BM * BK * 2;

  const int tid  = threadIdx.x;
  const int lane = tid & 63;
  const int wave = tid >> 6;
  const int wm = (wave >> 1) * 64;
  const int wn = (wave & 1) * 64;

  // XCD-aware swizzle: grid = 2048 (%8==0, bijective). n-tile in low bits so
  // each XCD keeps a contiguous A m-panel set hot in its private L2.
  const int per = gridDim.x >> 3;
  const int b   = blockIdx.x;
  const int swz = (b & 7) * per + (b >> 3);
  const int nt  = swz & 31;          // 32 n-tiles
  const int mt  = swz >> 5;          // 64 m-tiles
  const int row0 = mt * BM;
  const int col0 = nt * BN;

  f32x4 acc[4][4];
#pragma unroll
  for (int i = 0; i < 4; ++i)
#pragma unroll
    for (int j = 0; j < 4; ++j)
      acc[i][j] = f32x4{0.f, 0.f, 0.f, 0.f};

  // ---- staging constants ----
  // A: thread covers rows ar+32i (i=0..3), 8-float chunk ac.
  const int ar = tid >> 3;                 // 0..31
  const int ac = tid & 7;                  // 0..7
  const float* a_src = A + (size_t)(row0 + ar) * KDIM + ac * 8;
  const int a_off0 = (ar * 128 + ac * 16) ^ ((ar & 7) << 4);  // (ar+32i)&7==ar&7

  // B: thread covers packed row kp, 4 consecutive cols nl..nl+3.
  const int kp = tid >> 5;                 // 0..7
  const int nl = (tid & 31) * 4;           // 0..124
  const int* b_src = Bq + (size_t)kp * NDIM + col0 + nl;
  const float* s_src = S + col0 + nl;
  int bofs[4];
#pragma unroll
  for (int j = 0; j < 4; ++j) {
    const int r = nl + j;
    bofs[j] = (r * 128 + kp * 16) ^ ((((r & 7) ^ ((r >> 3) & 3))) << 4);
  }

  // fragment-read constants
  const int swzr = (lane & 7) << 4;
  const int arow = wm + (lane & 15);
  const int brow = wn + (lane & 15);
  const int kofs = (lane >> 4) << 4;

  float4 av[4][2];
  int4 bv;
  float4 sv;

  auto load_tile = [&](int kt) {
#pragma unroll
    for (int i = 0; i < 4; ++i) {
      const float* src = a_src + (size_t)i * 32 * KDIM + kt * BK;
      av[i][0] = *reinterpret_cast<const float4*>(src);
      av[i][1] = *reinterpret_cast<const float4*>(src + 4);
    }
    bv = *reinterpret_cast<const int4*>(b_src + (size_t)kt * 8 * NDIM);
    sv = *reinterpret_cast<const float4*>(s_src + (size_t)(kt >> 1) * NDIM);
  };

  auto stage_tile = [&]() {
    // A: fp32 -> fp16, k-permuted pairs (a_j, a_{j+4}), swizzled store
#pragma unroll
    for (int i = 0; i < 4; ++i) {
      uint4 w;
      w.x = cvt2(av[i][0].x, av[i][1].x);
      w.y = cvt2(av[i][0].y, av[i][1].y);
      w.z = cvt2(av[i][0].z, av[i][1].z);
      w.w = cvt2(av[i][0].w, av[i][1].w);
      *reinterpret_cast<uint4*>(As + a_off0 + i * 32 * 128) = w;
    }
    // B: nibble unpack (0x6400 trick), scale, swizzled store
    const __half2 k1032 = __float2half2_rn(1032.0f);
    const int bw[4] = {bv.x, bv.y, bv.z, bv.w};
    const float sc[4] = {sv.x, sv.y, sv.z, sv.w};
#pragma unroll
    for (int j = 0; j < 4; ++j) {
      const unsigned int ub = (unsigned int)bw[j];
      const unsigned int m4 = 0x000F000Fu, e10 = 0x64006400u;
      const __half2 sh = __float2half2_rn(sc[j]);
      uint4 w;   // k' order (n0,n4),(n1,n5),(n2,n6),(n3,n7) — matches A perm
      w.x = pack_dq((ub & m4) | e10, k1032, sh);
      w.y = pack_dq(((ub >> 4) & m4) | e10, k1032, sh);
      w.z = pack_dq(((ub >> 8) & m4) | e10, k1032, sh);
      w.w = pack_dq(((ub >> 12) & m4) | e10, k1032, sh);
      *reinterpret_cast<uint4*>(Bs + bofs[j]) = w;
    }
  };

  auto compute_tile = [&]() {
#pragma unroll
    for (int ks = 0; ks < 2; ++ks) {
      f16x8 af[4], bf[4];
#pragma unroll
      for (int mi = 0; mi < 4; ++mi) {
        const int o = ((arow + mi * 16) * 128 + ks * 64 + kofs) ^ swzr;
        af[mi] = *reinterpret_cast<const f16x8*>(As + o);
      }
#pragma unroll
      for (int ni = 0; ni < 4; ++ni) {
        const int r = brow + ni * 16;
        const int o = (r * 128 + ks * 64 + kofs) ^
                      ((((r & 7) ^ ((r >> 3) & 3))) << 4);
        bf[ni] = *reinterpret_cast<const f16x8*>(Bs + o);
      }
#pragma unroll
      for (int mi = 0; mi < 4; ++mi)
#pragma unroll
        for (int ni = 0; ni < 4; ++ni)
          acc[mi][ni] = __builtin_amdgcn_mfma_f32_16x16x32_f16(
              af[mi], bf[ni], acc[mi][ni], 0, 0, 0);
    }
  };

  // ---- pipelined main loop: issue loads kt+1 before compute kt ----
  load_tile(0);
  stage_tile();
  __syncthreads();
#pragma unroll 1
  for (int kt = 0; kt < KSTEPS; ++kt) {
    const bool has_next = (kt + 1) < KSTEPS;
    if (has_next) load_tile(kt + 1);   // in flight across compute
    compute_tile();
    if (has_next) {
      __syncthreads();                 // all waves done reading LDS
      stage_tile();                    // vmcnt wait lands here
      __syncthreads();
    }
  }

  // ---- epilogue: C/D layout col = lane&15, row = (lane>>4)*4 + reg ----
  const int crow = (lane >> 4) << 2;
  const int ccol = lane & 15;
#pragma unroll
  for (int mi = 0; mi < 4; ++mi)
#pragma unroll
    for (int ni = 0; ni < 4; ++ni) {
      const size_t base = (size_t)(row0 + wm + mi * 16 + crow) * NDIM
                          + (size_t)(col0 + wn + ni * 16 + ccol);
#pragma unroll
      for (int r = 0; r < 4; ++r)
        C[base + (size_t)r * NDIM] = acc[mi][ni][r];
    }
}

extern "C" void kernel_launch(void* const* d_in, const int* in_sizes, int n_in,
                              void* d_out, int out_size, void* d_ws, size_t ws_size,
                              hipStream_t stream) {
  (void)in_sizes; (void)n_in; (void)d_ws; (void)ws_size; (void)out_size;
  const float* A = (const float*)d_in[0];
  const int* Bq  = (const int*)d_in[1];
  const float* S = (const float*)d_in[2];
  float* C = (float*)d_out;
  const int grid = (MDIM / BM) * (NDIM / BN);   // 2048
  marlin_fused<<<grid, THREADS, 0, stream>>>(A, Bq, S, C);
}